// Round 6
// baseline (921.180 us; speedup 1.0000x reference)
//
#include <hip/hip_runtime.h>
#include <stdint.h>

typedef __attribute__((ext_vector_type(4))) float f4;
typedef __attribute__((ext_vector_type(8))) short bf16x8;
typedef unsigned short u16;

#define B_ 8
#define N_ 1024
#define C_ 768
#define NH 12
#define HD 64

__device__ __forceinline__ float bf2f(u16 v) {
  union { unsigned u; float f; } x; x.u = ((unsigned)v) << 16; return x.f;
}
__device__ __forceinline__ u16 f2bf(float f) {
  union { float f; unsigned u; } x; x.f = f;
  unsigned r = x.u + 0x7FFFu + ((x.u >> 16) & 1u);
  return (u16)(r >> 16);
}
__device__ __forceinline__ float ldn(float v, float lim) {
  return fminf(fmaxf(v, -lim), lim);
}

// ---------------- cvt: fp32 -> bf16, vectorized x4 ----------------
__global__ __launch_bounds__(256) void cvt_bf16(const float* __restrict__ s,
                                                u16* __restrict__ d, int n4) {
  int i = blockIdx.x * 256 + threadIdx.x;
  int stride = gridDim.x * 256;
  for (; i < n4; i += stride) {
    float4 v = ((const float4*)s)[i];
    ushort4 o;
    o.x = f2bf(v.x); o.y = f2bf(v.y); o.z = f2bf(v.z); o.w = f2bf(v.w);
    ((ushort4*)d)[i] = o;
  }
}

// ---------------- K0: LN stats ----------------
__global__ __launch_bounds__(256) void ln_stats(const float* __restrict__ y,
                                                float* __restrict__ mu,
                                                float* __restrict__ rs,
                                                int b0) {
  __shared__ float s1[4][64], s2[4][64];
  int t = threadIdx.x;
  int nl = t & 63, ch = t >> 6;
  int idx0 = b0 * N_ + blockIdx.x * 64;
  int b = idx0 >> 10, nb_ = idx0 & 1023;
  const float* p = y + (size_t)b * C_ * N_ + nb_ + nl;
  float s = 0.f, q = 0.f;
  int c0 = ch * 192;
  for (int c = c0; c < c0 + 192; ++c) {
    float v = p[(size_t)c * N_];
    s += v; q += v * v;
  }
  s1[ch][nl] = s; s2[ch][nl] = q;
  __syncthreads();
  if (t < 64) {
    float ts = s1[0][t] + s1[1][t] + s1[2][t] + s1[3][t];
    float tq = s2[0][t] + s2[1][t] + s2[2][t] + s2[3][t];
    float m = ts * (1.f / C_);
    float var = tq * (1.f / C_) - m * m;
    mu[idx0 + t] = ldn(m, 1e4f);
    rs[idx0 + t] = ldn(rsqrtf(fmaxf(var, 0.f) + 1e-5f), 1e6f);
  }
}

// ---------------- K1: transpose+normalize -> y2c bf16 ----------------
__global__ __launch_bounds__(256) void ln_apply(const float* __restrict__ y,
                                                const float* __restrict__ mu,
                                                const float* __restrict__ rs,
                                                const float* __restrict__ lg,
                                                const float* __restrict__ lb,
                                                u16* __restrict__ y2c,
                                                int b0) {
  __shared__ float tile[64][65];
  int t = threadIdx.x;
  int n0 = blockIdx.x * 64, c0 = blockIdx.y * 64;
  int bl = blockIdx.z, b = b0 + bl;
  int jc = (t & 15) * 4, ir = t >> 4;
  for (int r = 0; r < 4; ++r) {
    int i = ir + r * 16;
    float4 v = *(const float4*)(y + ((size_t)b * C_ + c0 + i) * N_ + n0 + jc);
    tile[i][jc] = v.x; tile[i][jc + 1] = v.y; tile[i][jc + 2] = v.z; tile[i][jc + 3] = v.w;
  }
  __syncthreads();
  for (int r = 0; r < 4; ++r) {
    int i = ir + r * 16;
    int n = n0 + i;
    float m = mu[b * N_ + n], rr = rs[b * N_ + n];
    float g0 = lg[c0 + jc],     b0f = lb[c0 + jc];
    float g1 = lg[c0 + jc + 1], b1f = lb[c0 + jc + 1];
    float g2 = lg[c0 + jc + 2], b2f = lb[c0 + jc + 2];
    float g3 = lg[c0 + jc + 3], b3f = lb[c0 + jc + 3];
    ushort4 o;
    o.x = f2bf(ldn((tile[jc][i] - m) * rr * g0 + b0f, 1e4f));
    o.y = f2bf(ldn((tile[jc + 1][i] - m) * rr * g1 + b1f, 1e4f));
    o.z = f2bf(ldn((tile[jc + 2][i] - m) * rr * g2 + b2f, 1e4f));
    o.w = f2bf(ldn((tile[jc + 3][i] - m) * rr * g3 + b3f, 1e4f));
    *(ushort4*)(y2c + ((size_t)bl * N_ + n) * C_ + c0 + jc) = o;
  }
}

// ---------------- K2: dual-A gated QKV GEMM, LDS-staged wide-store epilogue ----------------
// grid (18 col-tiles, nb*8 row-tiles): consecutive blocks share A rows (L2).
__global__ __launch_bounds__(256, 2) void gemm_qkv(
    const u16* __restrict__ xbc, const u16* __restrict__ y2c,
    const u16* __restrict__ qwb, const u16* __restrict__ kvwb,
    const float* __restrict__ qb, const float* __restrict__ kvb,
    u16* __restrict__ qoc, u16* __restrict__ koc, u16* __restrict__ vTc) {
  __shared__ u16 smem[128 * 136];      // 34816 B; K-loop uses first 12288 u16
  u16* Ax = smem;                       // 128*32
  u16* Ay = smem + 4096;
  u16* Bs = smem + 8192;
  int t = threadIdx.x, l = t & 63;
  int quad = l >> 4, l15 = l & 15;
  int w = t >> 6, wm = w & 1, wn = w >> 1;
  int n0 = blockIdx.x * 128;           // output-col tile (0..2303)
  int m0l = blockIdx.y * 128;          // chunk-local row tile
  const u16* wp; const float* bp; int sel, h0;
  if (n0 < C_)            { wp = qwb + (size_t)n0 * C_;          bp = qb + n0;         sel = 0; h0 = n0 >> 6; }
  else if (n0 < 2 * C_)   { wp = kvwb + (size_t)(n0 - C_) * C_;  bp = kvb + (n0 - C_); sel = 1; h0 = (n0 - C_) >> 6; }
  else                    { wp = kvwb + (size_t)(n0 - C_) * C_;  bp = kvb + (n0 - C_); sel = 2; h0 = (n0 - 2 * C_) >> 6; }

  f4 accx[4][4], accy[4][4];
  for (int i = 0; i < 4; ++i)
    for (int j = 0; j < 4; ++j) {
      accx[i][j] = (f4){0.f, 0.f, 0.f, 0.f};
      accy[i][j] = (f4){0.f, 0.f, 0.f, 0.f};
    }

  int row = t >> 2, colb = (t & 3) * 8;
  const u16* gx = xbc + (size_t)(m0l + row) * C_ + colb;
  const u16* gy = y2c + (size_t)(m0l + row) * C_ + colb;
  const u16* gw = wp + (size_t)row * C_ + colb;

  for (int kk = 0; kk < C_; kk += 32) {
    bf16x8 rx0 = *(const bf16x8*)(gx + kk);
    bf16x8 rx1 = *(const bf16x8*)(gx + kk + 64 * C_);
    bf16x8 ry0 = *(const bf16x8*)(gy + kk);
    bf16x8 ry1 = *(const bf16x8*)(gy + kk + 64 * C_);
    bf16x8 rw0 = *(const bf16x8*)(gw + kk);
    bf16x8 rw1 = *(const bf16x8*)(gw + kk + 64 * C_);
    __syncthreads();
    *(bf16x8*)&Ax[t * 8] = rx0;        *(bf16x8*)&Ax[2048 + t * 8] = rx1;
    *(bf16x8*)&Ay[t * 8] = ry0;        *(bf16x8*)&Ay[2048 + t * 8] = ry1;
    *(bf16x8*)&Bs[t * 8] = rw0;        *(bf16x8*)&Bs[2048 + t * 8] = rw1;
    __syncthreads();
    bf16x8 afx[4], afy[4], bfr[4];
    for (int i = 0; i < 4; ++i) {
      int ra = (wm * 64 + i * 16 + l15) * 32 + quad * 8;
      afx[i] = *(const bf16x8*)&Ax[ra];
      afy[i] = *(const bf16x8*)&Ay[ra];
      int rb = (wn * 64 + i * 16 + l15) * 32 + quad * 8;
      bfr[i] = *(const bf16x8*)&Bs[rb];
    }
    for (int i = 0; i < 4; ++i)
      for (int j = 0; j < 4; ++j) {
        accx[i][j] = __builtin_amdgcn_mfma_f32_16x16x32_bf16(afx[i], bfr[j], accx[i][j], 0, 0, 0);
        accy[i][j] = __builtin_amdgcn_mfma_f32_16x16x32_bf16(afy[i], bfr[j], accy[i][j], 0, 0, 0);
      }
  }

  // ---- epilogue: gate in regs -> LDS tile -> 16-B coalesced stores ----
  __syncthreads();                     // last frag reads done before reuse
  const int PITCH = 136;
  for (int j = 0; j < 4; ++j) {
    int cloc = wn * 64 + j * 16 + l15;
    float bias = bp[cloc];
    for (int i = 0; i < 4; ++i) {
      int rb0 = wm * 64 + i * 16 + quad * 4;
      for (int r = 0; r < 4; ++r) {
        int rloc = rb0 + r;
        float vx = ldn(accx[i][j][r] + bias, 1e4f);
        float vy = ldn(accy[i][j][r] + bias, 1e4f);
        float gg = 1.f / (1.f + __expf(-vy));
        float val = (sel == 0) ? vx * (1.f + gg) : gg * (vx + 1.f);
        u16 bv = f2bf(ldn(val, 2e4f));
        if (sel == 2) smem[cloc * PITCH + rloc] = bv;   // v staged transposed
        else          smem[rloc * PITCH + cloc] = bv;
      }
    }
  }
  __syncthreads();
  {
    int rr = t >> 1, hh = t & 1;       // 128 tile-rows x 2 col-halves
    const u16* src = smem + rr * PITCH + hh * 64;
    u16* dst;
    if (sel == 2) {
      int h = h0 + (rr >> 6), d = rr & 63;
      int bl = m0l >> 10, nbase = m0l & 1023;
      dst = vTc + (size_t)((bl * NH + h) * HD + d) * N_ + nbase + hh * 64;
    } else {
      int gml = m0l + rr;
      int bl = gml >> 10, n = gml & 1023;
      int h = h0 + hh;
      dst = (sel == 0 ? qoc : koc) + (size_t)((bl * NH + h) * N_ + n) * HD;
    }
    for (int c = 0; c < 8; ++c)
      *(bf16x8*)(dst + c * 8) = *(const bf16x8*)(src + c * 8);
  }
}

// ---------------- K3: fused attention, staged wide-store output ----------------
__global__ __launch_bounds__(256) void attn(const u16* __restrict__ qoc,
                                            const u16* __restrict__ koc,
                                            const u16* __restrict__ vTc,
                                            u16* __restrict__ aoc) {
  __shared__ u16 Qs[64 * 64], Ks[64 * 64], Vs[64 * 64];
  __shared__ u16 Ps[64 * 72];
  int t = threadIdx.x, l = t & 63, w = t >> 6;
  int quad = l >> 4, l15 = l & 15;
  int bhl = blockIdx.y;
  int bl = bhl / NH, h = bhl % NH;
  int q0 = blockIdx.x * 64;
  const u16* qbp = qoc + ((size_t)bhl * N_ + q0) * HD;
  *(bf16x8*)&Qs[t * 8]        = *(const bf16x8*)(qbp + (t >> 3) * HD + (t & 7) * 8);
  *(bf16x8*)&Qs[2048 + t * 8] = *(const bf16x8*)(qbp + (32 + (t >> 3)) * HD + (t & 7) * 8);
  __syncthreads();
  bf16x8 aq0 = *(const bf16x8*)&Qs[(w * 16 + l15) * 64 + quad * 8];
  bf16x8 aq1 = *(const bf16x8*)&Qs[(w * 16 + l15) * 64 + 32 + quad * 8];
  f4 o[4];
  for (int i = 0; i < 4; ++i) o[i] = (f4){0.f, 0.f, 0.f, 0.f};
  float lsum[4] = {0.f, 0.f, 0.f, 0.f};
  const u16* kb = koc + (size_t)bhl * N_ * HD;
  const u16* vb = vTc + (size_t)bhl * HD * N_;
  for (int kt = 0; kt < 16; ++kt) {
    int key0 = kt * 64;
    bf16x8 rk0 = *(const bf16x8*)(kb + (size_t)(key0 + (t >> 3)) * HD + (t & 7) * 8);
    bf16x8 rk1 = *(const bf16x8*)(kb + (size_t)(key0 + 32 + (t >> 3)) * HD + (t & 7) * 8);
    bf16x8 rv0 = *(const bf16x8*)(vb + (size_t)(t >> 3) * N_ + key0 + (t & 7) * 8);
    bf16x8 rv1 = *(const bf16x8*)(vb + (size_t)(32 + (t >> 3)) * N_ + key0 + (t & 7) * 8);
    __syncthreads();
    *(bf16x8*)&Ks[t * 8] = rk0;        *(bf16x8*)&Ks[2048 + t * 8] = rk1;
    *(bf16x8*)&Vs[t * 8] = rv0;        *(bf16x8*)&Vs[2048 + t * 8] = rv1;
    __syncthreads();
    f4 s[4];
    for (int ni = 0; ni < 4; ++ni) {
      bf16x8 b0v = *(const bf16x8*)&Ks[(ni * 16 + l15) * 64 + quad * 8];
      bf16x8 b1v = *(const bf16x8*)&Ks[(ni * 16 + l15) * 64 + 32 + quad * 8];
      f4 z = (f4){0.f, 0.f, 0.f, 0.f};
      z = __builtin_amdgcn_mfma_f32_16x16x32_bf16(aq0, b0v, z, 0, 0, 0);
      z = __builtin_amdgcn_mfma_f32_16x16x32_bf16(aq1, b1v, z, 0, 0, 0);
      s[ni] = z;
    }
    float p[4][4];
    for (int ni = 0; ni < 4; ++ni)
      for (int r = 0; r < 4; ++r)
        p[ni][r] = __expf(ldn(s[ni][r] * 0.125f, 30.f));
    for (int r = 0; r < 4; ++r) {
      float ts = p[0][r] + p[1][r] + p[2][r] + p[3][r];
      ts += __shfl_xor(ts, 1);
      ts += __shfl_xor(ts, 2);
      ts += __shfl_xor(ts, 4);
      ts += __shfl_xor(ts, 8);
      lsum[r] += ts;
    }
    // Ps rows [w*16, w*16+16) are wave-private: no barrier needed, only
    // same-wave write->read ordering (compiler inserts lgkmcnt).
    for (int ni = 0; ni < 4; ++ni)
      for (int r = 0; r < 4; ++r)
        Ps[(w * 16 + quad * 4 + r) * 72 + ni * 16 + l15] = f2bf(p[ni][r]);
    bf16x8 ap0 = *(const bf16x8*)&Ps[(w * 16 + l15) * 72 + quad * 8];
    bf16x8 ap1 = *(const bf16x8*)&Ps[(w * 16 + l15) * 72 + 32 + quad * 8];
    for (int ni = 0; ni < 4; ++ni) {
      bf16x8 b0v = *(const bf16x8*)&Vs[(ni * 16 + l15) * 64 + quad * 8];
      bf16x8 b1v = *(const bf16x8*)&Vs[(ni * 16 + l15) * 64 + 32 + quad * 8];
      o[ni] = __builtin_amdgcn_mfma_f32_16x16x32_bf16(ap0, b0v, o[ni], 0, 0, 0);
      o[ni] = __builtin_amdgcn_mfma_f32_16x16x32_bf16(ap1, b1v, o[ni], 0, 0, 0);
    }
  }
  // staged output: regs -> Ps -> 16-B coalesced stores
  for (int ni = 0; ni < 4; ++ni)
    for (int r = 0; r < 4; ++r)
      Ps[(w * 16 + quad * 4 + r) * 72 + ni * 16 + l15] =
          f2bf(ldn(o[ni][r] / fmaxf(lsum[r], 1e-30f), 1e4f));
  __syncthreads();
  {
    int rr = t >> 2, cc = t & 3;       // 64 rows x 4 chunks of 16 u16
    int n = q0 + rr;
    const u16* src = Ps + rr * 72 + cc * 16;
    u16* dst = aoc + ((size_t)bl * N_ + n) * C_ + h * HD + cc * 16;
    *(bf16x8*)dst = *(const bf16x8*)src;
    *(bf16x8*)(dst + 8) = *(const bf16x8*)(src + 8);
  }
}

// ---------------- K4: output projection GEMM (bf16 compute, fp32 out) ----------------
__global__ __launch_bounds__(256, 2) void gemm_proj(const u16* __restrict__ aoc,
                                                    const u16* __restrict__ pwb,
                                                    const float* __restrict__ bias,
                                                    float* __restrict__ out,
                                                    int b0) {
  __shared__ u16 As[128 * 32], Bs[128 * 32];
  int t = threadIdx.x, l = t & 63;
  int quad = l >> 4, l15 = l & 15;
  int w = t >> 6, wm = w & 1, wn = w >> 1;
  int m0l = blockIdx.x * 128, n0 = blockIdx.y * 128;
  f4 acc[4][4];
  for (int i = 0; i < 4; ++i)
    for (int j = 0; j < 4; ++j) acc[i][j] = (f4){0.f, 0.f, 0.f, 0.f};
  int row = t >> 2, colb = (t & 3) * 8;
  const u16* ga = aoc + (size_t)(m0l + row) * C_ + colb;
  const u16* gw = pwb + (size_t)(n0 + row) * C_ + colb;
  for (int kk = 0; kk < C_; kk += 32) {
    bf16x8 ra0 = *(const bf16x8*)(ga + kk);
    bf16x8 ra1 = *(const bf16x8*)(ga + kk + 64 * C_);
    bf16x8 rw0 = *(const bf16x8*)(gw + kk);
    bf16x8 rw1 = *(const bf16x8*)(gw + kk + 64 * C_);
    __syncthreads();
    *(bf16x8*)&As[t * 8] = ra0;        *(bf16x8*)&As[2048 + t * 8] = ra1;
    *(bf16x8*)&Bs[t * 8] = rw0;        *(bf16x8*)&Bs[2048 + t * 8] = rw1;
    __syncthreads();
    bf16x8 af[4], bfr[4];
    for (int i = 0; i < 4; ++i) {
      af[i]  = *(const bf16x8*)&As[(wm * 64 + i * 16 + l15) * 32 + quad * 8];
      bfr[i] = *(const bf16x8*)&Bs[(wn * 64 + i * 16 + l15) * 32 + quad * 8];
    }
    for (int i = 0; i < 4; ++i)
      for (int j = 0; j < 4; ++j)
        acc[i][j] = __builtin_amdgcn_mfma_f32_16x16x32_bf16(af[i], bfr[j], acc[i][j], 0, 0, 0);
  }
  for (int j = 0; j < 4; ++j) {
    int gcol = n0 + wn * 64 + j * 16 + l15;
    float bv = bias[gcol];
    for (int i = 0; i < 4; ++i) {
      int rbase = m0l + wm * 64 + i * 16 + quad * 4;
      for (int r = 0; r < 4; ++r)
        out[(size_t)(b0 * N_ + rbase + r) * C_ + gcol] = ldn(acc[i][j][r] + bv, 1e4f);
    }
  }
}

extern "C" void kernel_launch(void* const* d_in, const int* in_sizes, int n_in,
                              void* d_out, int out_size, void* d_ws, size_t ws_size,
                              hipStream_t stream) {
  const float* x   = (const float*)d_in[0];
  const float* y   = (const float*)d_in[1];
  const float* qw  = (const float*)d_in[2];
  const float* qb  = (const float*)d_in[3];
  const float* kvw = (const float*)d_in[4];
  const float* kvb = (const float*)d_in[5];
  const float* pw  = (const float*)d_in[6];
  const float* pb  = (const float*)d_in[7];
  const float* lg  = (const float*)d_in[8];
  const float* lb  = (const float*)d_in[9];

  char* ws = (char*)d_ws;
  float* mu = (float*)(ws);                       // 32 KB
  float* rs = (float*)(ws + 32768);               // 32 KB
  u16* qwb  = (u16*)(ws + 65536);                 // 1179648 B
  u16* kvwb = (u16*)(ws + 1245184);               // 2359296 B
  u16* pwb  = (u16*)(ws + 3604480);               // 1179648 B
  const size_t BASE2 = 4784128;
  const size_t PER_B = 1572864;                   // one [1024,768] bf16 tensor

  // 5 chunk buffers: xbc, y2c, qoc, koc, vTc; aoc aliases xbc (dead after qkv).
  int nb = 1;
  for (int c = 8; c >= 1; c >>= 1) {
    if (BASE2 + 5 * (size_t)c * PER_B <= ws_size) { nb = c; break; }
  }
  u16* xbc = (u16*)(ws + BASE2);
  u16* y2c = (u16*)(ws + BASE2 + (size_t)nb * PER_B);
  u16* qoc = (u16*)(ws + BASE2 + 2 * (size_t)nb * PER_B);
  u16* koc = (u16*)(ws + BASE2 + 3 * (size_t)nb * PER_B);
  u16* vTc = (u16*)(ws + BASE2 + 4 * (size_t)nb * PER_B);
  u16* aoc = xbc;

  cvt_bf16<<<dim3(576), dim3(256), 0, stream>>>(qw, qwb, 147456);
  cvt_bf16<<<dim3(1152), dim3(256), 0, stream>>>(kvw, kvwb, 294912);
  cvt_bf16<<<dim3(576), dim3(256), 0, stream>>>(pw, pwb, 147456);

  for (int b0 = 0; b0 < B_; b0 += nb) {
    cvt_bf16<<<dim3(768 * nb), dim3(256), 0, stream>>>(
        x + (size_t)b0 * N_ * C_, xbc, nb * 196608);
    ln_stats<<<dim3(16 * nb), dim3(256), 0, stream>>>(y, mu, rs, b0);
    ln_apply<<<dim3(16, 12, nb), dim3(256), 0, stream>>>(y, mu, rs, lg, lb, y2c, b0);
    gemm_qkv<<<dim3(18, 8 * nb), dim3(256), 0, stream>>>(xbc, y2c, qwb, kvwb, qb, kvb,
                                                         qoc, koc, vTc);
    attn<<<dim3(16, 12 * nb), dim3(256), 0, stream>>>(qoc, koc, vTc, aoc);
    gemm_proj<<<dim3(8 * nb, 6), dim3(256), 0, stream>>>(aoc, pwb, pb, (float*)d_out, b0);
  }
}

// Round 7
// 874.278 us; speedup vs baseline: 1.0536x; 1.0536x over previous
//
#include <hip/hip_runtime.h>
#include <stdint.h>

typedef __attribute__((ext_vector_type(4))) float f4;
typedef __attribute__((ext_vector_type(8))) short bf16x8;
typedef unsigned short u16;

#define B_ 8
#define N_ 1024
#define C_ 768
#define NH 12
#define HD 64

__device__ __forceinline__ float bf2f(u16 v) {
  union { unsigned u; float f; } x; x.u = ((unsigned)v) << 16; return x.f;
}
__device__ __forceinline__ u16 f2bf(float f) {
  union { float f; unsigned u; } x; x.f = f;
  unsigned r = x.u + 0x7FFFu + ((x.u >> 16) & 1u);
  return (u16)(r >> 16);
}
__device__ __forceinline__ float ldn(float v, float lim) {
  return fminf(fmaxf(v, -lim), lim);
}
// async global->LDS, 16B per lane. LDS dest = firstlane(ptr) + lane*16;
// passing base + tid*8 (u16) yields tid*16 bytes per thread. [m97-verified]
__device__ __forceinline__ void g2l16(const u16* g, const u16* l) {
  __builtin_amdgcn_global_load_lds(
      (const __attribute__((address_space(1))) void*)(uintptr_t)g,
      (__attribute__((address_space(3))) void*)(uint32_t)(uintptr_t)l,
      16, 0, 0);
}

// ---------------- cvt: fp32 -> bf16, vectorized x4 ----------------
__global__ __launch_bounds__(256) void cvt_bf16(const float* __restrict__ s,
                                                u16* __restrict__ d, int n4) {
  int i = blockIdx.x * 256 + threadIdx.x;
  int stride = gridDim.x * 256;
  for (; i < n4; i += stride) {
    float4 v = ((const float4*)s)[i];
    ushort4 o;
    o.x = f2bf(v.x); o.y = f2bf(v.y); o.z = f2bf(v.z); o.w = f2bf(v.w);
    ((ushort4*)d)[i] = o;
  }
}

// ---------------- K0: LN stats ----------------
__global__ __launch_bounds__(256) void ln_stats(const float* __restrict__ y,
                                                float* __restrict__ mu,
                                                float* __restrict__ rs,
                                                int b0) {
  __shared__ float s1[4][64], s2[4][64];
  int t = threadIdx.x;
  int nl = t & 63, ch = t >> 6;
  int idx0 = b0 * N_ + blockIdx.x * 64;
  int b = idx0 >> 10, nb_ = idx0 & 1023;
  const float* p = y + (size_t)b * C_ * N_ + nb_ + nl;
  float s = 0.f, q = 0.f;
  int c0 = ch * 192;
  for (int c = c0; c < c0 + 192; ++c) {
    float v = p[(size_t)c * N_];
    s += v; q += v * v;
  }
  s1[ch][nl] = s; s2[ch][nl] = q;
  __syncthreads();
  if (t < 64) {
    float ts = s1[0][t] + s1[1][t] + s1[2][t] + s1[3][t];
    float tq = s2[0][t] + s2[1][t] + s2[2][t] + s2[3][t];
    float m = ts * (1.f / C_);
    float var = tq * (1.f / C_) - m * m;
    mu[idx0 + t] = ldn(m, 1e4f);
    rs[idx0 + t] = ldn(rsqrtf(fmaxf(var, 0.f) + 1e-5f), 1e6f);
  }
}

// ---------------- K1: transpose+normalize -> y2c bf16 ----------------
__global__ __launch_bounds__(256) void ln_apply(const float* __restrict__ y,
                                                const float* __restrict__ mu,
                                                const float* __restrict__ rs,
                                                const float* __restrict__ lg,
                                                const float* __restrict__ lb,
                                                u16* __restrict__ y2c,
                                                int b0) {
  __shared__ float tile[64][65];
  int t = threadIdx.x;
  int n0 = blockIdx.x * 64, c0 = blockIdx.y * 64;
  int bl = blockIdx.z, b = b0 + bl;
  int jc = (t & 15) * 4, ir = t >> 4;
  for (int r = 0; r < 4; ++r) {
    int i = ir + r * 16;
    float4 v = *(const float4*)(y + ((size_t)b * C_ + c0 + i) * N_ + n0 + jc);
    tile[i][jc] = v.x; tile[i][jc + 1] = v.y; tile[i][jc + 2] = v.z; tile[i][jc + 3] = v.w;
  }
  __syncthreads();
  for (int r = 0; r < 4; ++r) {
    int i = ir + r * 16;
    int n = n0 + i;
    float m = mu[b * N_ + n], rr = rs[b * N_ + n];
    float g0 = lg[c0 + jc],     b0f = lb[c0 + jc];
    float g1 = lg[c0 + jc + 1], b1f = lb[c0 + jc + 1];
    float g2 = lg[c0 + jc + 2], b2f = lb[c0 + jc + 2];
    float g3 = lg[c0 + jc + 3], b3f = lb[c0 + jc + 3];
    ushort4 o;
    o.x = f2bf(ldn((tile[jc][i] - m) * rr * g0 + b0f, 1e4f));
    o.y = f2bf(ldn((tile[jc + 1][i] - m) * rr * g1 + b1f, 1e4f));
    o.z = f2bf(ldn((tile[jc + 2][i] - m) * rr * g2 + b2f, 1e4f));
    o.w = f2bf(ldn((tile[jc + 3][i] - m) * rr * g3 + b3f, 1e4f));
    *(ushort4*)(y2c + ((size_t)bl * N_ + n) * C_ + c0 + jc) = o;
  }
}

// ---------------- K2: dual-A gated QKV GEMM, async LDS staging ----------------
// grid (8*nb row-tiles, 18 col-tiles). No staging VGPRs -> no spills.
__global__ __launch_bounds__(256, 2) void gemm_qkv(
    const u16* __restrict__ xbc, const u16* __restrict__ y2c,
    const u16* __restrict__ qwb, const u16* __restrict__ kvwb,
    const float* __restrict__ qb, const float* __restrict__ kvb,
    u16* __restrict__ qoc, u16* __restrict__ koc, u16* __restrict__ vTc) {
  __shared__ u16 smem[128 * 136];      // 34816 B; K-loop uses first 12288 u16
  u16* Ax = smem;                       // 128*32
  u16* Ay = smem + 4096;
  u16* Bs = smem + 8192;
  int t = threadIdx.x, l = t & 63;
  int quad = l >> 4, l15 = l & 15;
  int w = t >> 6, wm = w & 1, wn = w >> 1;
  int m0l = blockIdx.x * 128;          // chunk-local row tile
  int n0 = blockIdx.y * 128;           // output-col tile (0..2303)
  const u16* wp; const float* bp; int sel, h0;
  if (n0 < C_)            { wp = qwb + (size_t)n0 * C_;          bp = qb + n0;         sel = 0; h0 = n0 >> 6; }
  else if (n0 < 2 * C_)   { wp = kvwb + (size_t)(n0 - C_) * C_;  bp = kvb + (n0 - C_); sel = 1; h0 = (n0 - C_) >> 6; }
  else                    { wp = kvwb + (size_t)(n0 - C_) * C_;  bp = kvb + (n0 - C_); sel = 2; h0 = (n0 - 2 * C_) >> 6; }

  f4 accx[4][4], accy[4][4];
  for (int i = 0; i < 4; ++i)
    for (int j = 0; j < 4; ++j) {
      accx[i][j] = (f4){0.f, 0.f, 0.f, 0.f};
      accy[i][j] = (f4){0.f, 0.f, 0.f, 0.f};
    }

  int row = t >> 2, colb = (t & 3) * 8;
  const u16* gx = xbc + (size_t)(m0l + row) * C_ + colb;
  const u16* gy = y2c + (size_t)(m0l + row) * C_ + colb;
  const u16* gw = wp + (size_t)row * C_ + colb;

  for (int kk = 0; kk < C_; kk += 32) {
    __syncthreads();                   // previous iteration's frag reads done
    g2l16(gx + kk,           Ax + t * 8);
    g2l16(gx + kk + 64 * C_, Ax + 2048 + t * 8);
    g2l16(gy + kk,           Ay + t * 8);
    g2l16(gy + kk + 64 * C_, Ay + 2048 + t * 8);
    g2l16(gw + kk,           Bs + t * 8);
    g2l16(gw + kk + 64 * C_, Bs + 2048 + t * 8);
    __syncthreads();                   // drains vmcnt: LDS data visible
    bf16x8 afx[4], afy[4], bfr[4];
    for (int i = 0; i < 4; ++i) {
      int ra = (wm * 64 + i * 16 + l15) * 32 + quad * 8;
      afx[i] = *(const bf16x8*)&Ax[ra];
      afy[i] = *(const bf16x8*)&Ay[ra];
      int rb = (wn * 64 + i * 16 + l15) * 32 + quad * 8;
      bfr[i] = *(const bf16x8*)&Bs[rb];
    }
    for (int i = 0; i < 4; ++i)
      for (int j = 0; j < 4; ++j) {
        accx[i][j] = __builtin_amdgcn_mfma_f32_16x16x32_bf16(afx[i], bfr[j], accx[i][j], 0, 0, 0);
        accy[i][j] = __builtin_amdgcn_mfma_f32_16x16x32_bf16(afy[i], bfr[j], accy[i][j], 0, 0, 0);
      }
  }

  // ---- epilogue: gate in regs -> LDS tile -> 16-B coalesced stores ----
  __syncthreads();
  const int PITCH = 136;
  for (int j = 0; j < 4; ++j) {
    int cloc = wn * 64 + j * 16 + l15;
    float bias = bp[cloc];
    for (int i = 0; i < 4; ++i) {
      int rb0 = wm * 64 + i * 16 + quad * 4;
      for (int r = 0; r < 4; ++r) {
        int rloc = rb0 + r;
        float vx = ldn(accx[i][j][r] + bias, 1e4f);
        float vy = ldn(accy[i][j][r] + bias, 1e4f);
        float gg = 1.f / (1.f + __expf(-vy));
        float val = (sel == 0) ? vx * (1.f + gg) : gg * (vx + 1.f);
        u16 bv = f2bf(ldn(val, 2e4f));
        if (sel == 2) smem[cloc * PITCH + rloc] = bv;   // v staged transposed
        else          smem[rloc * PITCH + cloc] = bv;
      }
    }
  }
  __syncthreads();
  {
    int rr = t >> 1, hh = t & 1;       // 128 tile-rows x 2 col-halves
    const u16* src = smem + rr * PITCH + hh * 64;
    u16* dst;
    if (sel == 2) {
      int h = h0 + (rr >> 6), d = rr & 63;
      int bl = m0l >> 10, nbase = m0l & 1023;
      dst = vTc + (size_t)((bl * NH + h) * HD + d) * N_ + nbase + hh * 64;
    } else {
      int gml = m0l + rr;
      int bl = gml >> 10, n = gml & 1023;
      int h = h0 + hh;
      dst = (sel == 0 ? qoc : koc) + (size_t)((bl * NH + h) * N_ + n) * HD;
    }
    for (int c = 0; c < 8; ++c)
      *(bf16x8*)(dst + c * 8) = *(const bf16x8*)(src + c * 8);
  }
}

// ---------------- K3: fused attention, async staging ----------------
__global__ __launch_bounds__(256) void attn(const u16* __restrict__ qoc,
                                            const u16* __restrict__ koc,
                                            const u16* __restrict__ vTc,
                                            u16* __restrict__ aoc) {
  __shared__ u16 Qs[64 * 64], Ks[64 * 64], Vs[64 * 64];
  __shared__ u16 Ps[64 * 72];
  int t = threadIdx.x, l = t & 63, w = t >> 6;
  int quad = l >> 4, l15 = l & 15;
  int bhl = blockIdx.y;
  int bl = bhl / NH, h = bhl % NH;
  int q0 = blockIdx.x * 64;
  const u16* qbp = qoc + ((size_t)bhl * N_ + q0) * HD;
  g2l16(qbp + (t >> 3) * HD + (t & 7) * 8,        Qs + t * 8);
  g2l16(qbp + (32 + (t >> 3)) * HD + (t & 7) * 8, Qs + 2048 + t * 8);
  __syncthreads();
  bf16x8 aq0 = *(const bf16x8*)&Qs[(w * 16 + l15) * 64 + quad * 8];
  bf16x8 aq1 = *(const bf16x8*)&Qs[(w * 16 + l15) * 64 + 32 + quad * 8];
  f4 o[4];
  for (int i = 0; i < 4; ++i) o[i] = (f4){0.f, 0.f, 0.f, 0.f};
  float lsum[4] = {0.f, 0.f, 0.f, 0.f};
  const u16* kb = koc + (size_t)bhl * N_ * HD;
  const u16* vb = vTc + (size_t)bhl * HD * N_;
  for (int kt = 0; kt < 16; ++kt) {
    int key0 = kt * 64;
    __syncthreads();                   // previous iter's K/V reads done
    g2l16(kb + (size_t)(key0 + (t >> 3)) * HD + (t & 7) * 8,      Ks + t * 8);
    g2l16(kb + (size_t)(key0 + 32 + (t >> 3)) * HD + (t & 7) * 8, Ks + 2048 + t * 8);
    g2l16(vb + (size_t)(t >> 3) * N_ + key0 + (t & 7) * 8,        Vs + t * 8);
    g2l16(vb + (size_t)(32 + (t >> 3)) * N_ + key0 + (t & 7) * 8, Vs + 2048 + t * 8);
    __syncthreads();
    f4 s[4];
    for (int ni = 0; ni < 4; ++ni) {
      bf16x8 b0v = *(const bf16x8*)&Ks[(ni * 16 + l15) * 64 + quad * 8];
      bf16x8 b1v = *(const bf16x8*)&Ks[(ni * 16 + l15) * 64 + 32 + quad * 8];
      f4 z = (f4){0.f, 0.f, 0.f, 0.f};
      z = __builtin_amdgcn_mfma_f32_16x16x32_bf16(aq0, b0v, z, 0, 0, 0);
      z = __builtin_amdgcn_mfma_f32_16x16x32_bf16(aq1, b1v, z, 0, 0, 0);
      s[ni] = z;
    }
    float p[4][4];
    for (int ni = 0; ni < 4; ++ni)
      for (int r = 0; r < 4; ++r)
        p[ni][r] = __expf(ldn(s[ni][r] * 0.125f, 30.f));
    for (int r = 0; r < 4; ++r) {
      float ts = p[0][r] + p[1][r] + p[2][r] + p[3][r];
      ts += __shfl_xor(ts, 1);
      ts += __shfl_xor(ts, 2);
      ts += __shfl_xor(ts, 4);
      ts += __shfl_xor(ts, 8);
      lsum[r] += ts;
    }
    // Ps rows [w*16, w*16+16) are wave-private: same-wave lgkmcnt ordering only.
    for (int ni = 0; ni < 4; ++ni)
      for (int r = 0; r < 4; ++r)
        Ps[(w * 16 + quad * 4 + r) * 72 + ni * 16 + l15] = f2bf(p[ni][r]);
    bf16x8 ap0 = *(const bf16x8*)&Ps[(w * 16 + l15) * 72 + quad * 8];
    bf16x8 ap1 = *(const bf16x8*)&Ps[(w * 16 + l15) * 72 + 32 + quad * 8];
    for (int ni = 0; ni < 4; ++ni) {
      bf16x8 b0v = *(const bf16x8*)&Vs[(ni * 16 + l15) * 64 + quad * 8];
      bf16x8 b1v = *(const bf16x8*)&Vs[(ni * 16 + l15) * 64 + 32 + quad * 8];
      o[ni] = __builtin_amdgcn_mfma_f32_16x16x32_bf16(ap0, b0v, o[ni], 0, 0, 0);
      o[ni] = __builtin_amdgcn_mfma_f32_16x16x32_bf16(ap1, b1v, o[ni], 0, 0, 0);
    }
  }
  // staged output: regs -> Ps -> 16-B coalesced stores
  for (int ni = 0; ni < 4; ++ni)
    for (int r = 0; r < 4; ++r)
      Ps[(w * 16 + quad * 4 + r) * 72 + ni * 16 + l15] =
          f2bf(ldn(o[ni][r] / fmaxf(lsum[r], 1e-30f), 1e4f));
  __syncthreads();
  {
    int rr = t >> 2, cc = t & 3;       // 64 rows x 4 chunks of 16 u16
    int n = q0 + rr;
    const u16* src = Ps + rr * 72 + cc * 16;
    u16* dst = aoc + ((size_t)bl * N_ + n) * C_ + h * HD + cc * 16;
    *(bf16x8*)dst = *(const bf16x8*)src;
    *(bf16x8*)(dst + 8) = *(const bf16x8*)(src + 8);
  }
}

// ---------------- K4: output projection GEMM, async staging ----------------
__global__ __launch_bounds__(256, 2) void gemm_proj(const u16* __restrict__ aoc,
                                                    const u16* __restrict__ pwb,
                                                    const float* __restrict__ bias,
                                                    float* __restrict__ out,
                                                    int b0) {
  __shared__ u16 As[128 * 32], Bs[128 * 32];
  int t = threadIdx.x, l = t & 63;
  int quad = l >> 4, l15 = l & 15;
  int w = t >> 6, wm = w & 1, wn = w >> 1;
  int m0l = blockIdx.x * 128, n0 = blockIdx.y * 128;
  f4 acc[4][4];
  for (int i = 0; i < 4; ++i)
    for (int j = 0; j < 4; ++j) acc[i][j] = (f4){0.f, 0.f, 0.f, 0.f};
  int row = t >> 2, colb = (t & 3) * 8;
  const u16* ga = aoc + (size_t)(m0l + row) * C_ + colb;
  const u16* gw = pwb + (size_t)(n0 + row) * C_ + colb;
  for (int kk = 0; kk < C_; kk += 32) {
    __syncthreads();
    g2l16(ga + kk,           As + t * 8);
    g2l16(ga + kk + 64 * C_, As + 2048 + t * 8);
    g2l16(gw + kk,           Bs + t * 8);
    g2l16(gw + kk + 64 * C_, Bs + 2048 + t * 8);
    __syncthreads();
    bf16x8 af[4], bfr[4];
    for (int i = 0; i < 4; ++i) {
      af[i]  = *(const bf16x8*)&As[(wm * 64 + i * 16 + l15) * 32 + quad * 8];
      bfr[i] = *(const bf16x8*)&Bs[(wn * 64 + i * 16 + l15) * 32 + quad * 8];
    }
    for (int i = 0; i < 4; ++i)
      for (int j = 0; j < 4; ++j)
        acc[i][j] = __builtin_amdgcn_mfma_f32_16x16x32_bf16(af[i], bfr[j], acc[i][j], 0, 0, 0);
  }
  for (int j = 0; j < 4; ++j) {
    int gcol = n0 + wn * 64 + j * 16 + l15;
    float bv = bias[gcol];
    for (int i = 0; i < 4; ++i) {
      int rbase = m0l + wm * 64 + i * 16 + quad * 4;
      for (int r = 0; r < 4; ++r)
        out[(size_t)(b0 * N_ + rbase + r) * C_ + gcol] = ldn(acc[i][j][r] + bv, 1e4f);
    }
  }
}

extern "C" void kernel_launch(void* const* d_in, const int* in_sizes, int n_in,
                              void* d_out, int out_size, void* d_ws, size_t ws_size,
                              hipStream_t stream) {
  const float* x   = (const float*)d_in[0];
  const float* y   = (const float*)d_in[1];
  const float* qw  = (const float*)d_in[2];
  const float* qb  = (const float*)d_in[3];
  const float* kvw = (const float*)d_in[4];
  const float* kvb = (const float*)d_in[5];
  const float* pw  = (const float*)d_in[6];
  const float* pb  = (const float*)d_in[7];
  const float* lg  = (const float*)d_in[8];
  const float* lb  = (const float*)d_in[9];

  char* ws = (char*)d_ws;
  float* mu = (float*)(ws);                       // 32 KB
  float* rs = (float*)(ws + 32768);               // 32 KB
  u16* qwb  = (u16*)(ws + 65536);                 // 1179648 B
  u16* kvwb = (u16*)(ws + 1245184);               // 2359296 B
  u16* pwb  = (u16*)(ws + 3604480);               // 1179648 B
  const size_t BASE2 = 4784128;
  const size_t PER_B = 1572864;                   // one [1024,768] bf16 tensor

  // 5 chunk buffers: xbc, y2c, qoc, koc, vTc; aoc aliases xbc (dead after qkv).
  int nb = 1;
  for (int c = 8; c >= 1; c >>= 1) {
    if (BASE2 + 5 * (size_t)c * PER_B <= ws_size) { nb = c; break; }
  }
  u16* xbc = (u16*)(ws + BASE2);
  u16* y2c = (u16*)(ws + BASE2 + (size_t)nb * PER_B);
  u16* qoc = (u16*)(ws + BASE2 + 2 * (size_t)nb * PER_B);
  u16* koc = (u16*)(ws + BASE2 + 3 * (size_t)nb * PER_B);
  u16* vTc = (u16*)(ws + BASE2 + 4 * (size_t)nb * PER_B);
  u16* aoc = xbc;

  cvt_bf16<<<dim3(576), dim3(256), 0, stream>>>(qw, qwb, 147456);
  cvt_bf16<<<dim3(1152), dim3(256), 0, stream>>>(kvw, kvwb, 294912);
  cvt_bf16<<<dim3(576), dim3(256), 0, stream>>>(pw, pwb, 147456);

  for (int b0 = 0; b0 < B_; b0 += nb) {
    cvt_bf16<<<dim3(768 * nb), dim3(256), 0, stream>>>(
        x + (size_t)b0 * N_ * C_, xbc, nb * 196608);
    ln_stats<<<dim3(16 * nb), dim3(256), 0, stream>>>(y, mu, rs, b0);
    ln_apply<<<dim3(16, 12, nb), dim3(256), 0, stream>>>(y, mu, rs, lg, lb, y2c, b0);
    gemm_qkv<<<dim3(8 * nb, 18), dim3(256), 0, stream>>>(xbc, y2c, qwb, kvwb, qb, kvb,
                                                         qoc, koc, vTc);
    attn<<<dim3(16, 12 * nb), dim3(256), 0, stream>>>(qoc, koc, vTc, aoc);
    gemm_proj<<<dim3(8 * nb, 6), dim3(256), 0, stream>>>(aoc, pwb, pb, (float*)d_out, b0);
  }
}

// Round 9
// 395.144 us; speedup vs baseline: 2.3313x; 2.2126x over previous
//
#include <hip/hip_runtime.h>
#include <stdint.h>

typedef __attribute__((ext_vector_type(4))) float f4;
typedef __attribute__((ext_vector_type(8))) short bf16x8;
typedef __attribute__((ext_vector_type(4))) unsigned short u16x4;
typedef unsigned short u16;

#define B_ 8
#define N_ 1024
#define C_ 768
#define NH 12
#define HD 64

__device__ __forceinline__ float bf2f(u16 v) {
  union { unsigned u; float f; } x; x.u = ((unsigned)v) << 16; return x.f;
}
__device__ __forceinline__ u16 f2bf(float f) {
  union { float f; unsigned u; } x; x.f = f;
  unsigned r = x.u + 0x7FFFu + ((x.u >> 16) & 1u);
  return (u16)(r >> 16);
}
// async global->LDS, 16B per lane; lds dest = firstlane + lane*16 (m97 pattern)
__device__ __forceinline__ void g2l16(const u16* g, const u16* l) {
  __builtin_amdgcn_global_load_lds(
      (const __attribute__((address_space(1))) void*)(uintptr_t)g,
      (__attribute__((address_space(3))) void*)(uint32_t)(uintptr_t)l,
      16, 0, 0);
}

// ---------------- cvt: fp32 -> bf16, vectorized x4 ----------------
__global__ __launch_bounds__(256) void cvt_bf16(const float* __restrict__ s,
                                                u16* __restrict__ d, int n4) {
  int i = blockIdx.x * 256 + threadIdx.x;
  int stride = gridDim.x * 256;
  for (; i < n4; i += stride) {
    float4 v = ((const float4*)s)[i];
    u16x4 o;
    o.x = f2bf(v.x); o.y = f2bf(v.y); o.z = f2bf(v.z); o.w = f2bf(v.w);
    __builtin_nontemporal_store(o, (u16x4*)d + i);
  }
}

// ---------------- K0: LN stats ----------------
__global__ __launch_bounds__(256) void ln_stats(const float* __restrict__ y,
                                                float* __restrict__ mu,
                                                float* __restrict__ rs,
                                                int b0) {
  __shared__ float s1[4][64], s2[4][64];
  int t = threadIdx.x;
  int nl = t & 63, ch = t >> 6;
  int idx0 = b0 * N_ + blockIdx.x * 64;
  int b = idx0 >> 10, nb_ = idx0 & 1023;
  const float* p = y + (size_t)b * C_ * N_ + nb_ + nl;
  float s = 0.f, q = 0.f;
  int c0 = ch * 192;
  for (int c = c0; c < c0 + 192; ++c) {
    float v = p[(size_t)c * N_];
    s += v; q += v * v;
  }
  s1[ch][nl] = s; s2[ch][nl] = q;
  __syncthreads();
  if (t < 64) {
    float ts = s1[0][t] + s1[1][t] + s1[2][t] + s1[3][t];
    float tq = s2[0][t] + s2[1][t] + s2[2][t] + s2[3][t];
    float m = ts * (1.f / C_);
    float var = tq * (1.f / C_) - m * m;
    mu[idx0 + t] = m;
    rs[idx0 + t] = rsqrtf(fmaxf(var, 0.f) + 1e-5f);
  }
}

// ---------------- K1: transpose+normalize -> y2c bf16 ----------------
__global__ __launch_bounds__(256) void ln_apply(const float* __restrict__ y,
                                                const float* __restrict__ mu,
                                                const float* __restrict__ rs,
                                                const float* __restrict__ lg,
                                                const float* __restrict__ lb,
                                                u16* __restrict__ y2c,
                                                int b0) {
  __shared__ float tile[64][65];
  int t = threadIdx.x;
  int n0 = blockIdx.x * 64, c0 = blockIdx.y * 64;
  int bl = blockIdx.z, b = b0 + bl;
  int jc = (t & 15) * 4, ir = t >> 4;
  for (int r = 0; r < 4; ++r) {
    int i = ir + r * 16;
    float4 v = *(const float4*)(y + ((size_t)b * C_ + c0 + i) * N_ + n0 + jc);
    tile[i][jc] = v.x; tile[i][jc + 1] = v.y; tile[i][jc + 2] = v.z; tile[i][jc + 3] = v.w;
  }
  __syncthreads();
  for (int r = 0; r < 4; ++r) {
    int i = ir + r * 16;
    int n = n0 + i;
    float m = mu[b * N_ + n], rr = rs[b * N_ + n];
    float g0 = lg[c0 + jc],     b0f = lb[c0 + jc];
    float g1 = lg[c0 + jc + 1], b1f = lb[c0 + jc + 1];
    float g2 = lg[c0 + jc + 2], b2f = lb[c0 + jc + 2];
    float g3 = lg[c0 + jc + 3], b3f = lb[c0 + jc + 3];
    u16x4 o;
    o.x = f2bf((tile[jc][i] - m) * rr * g0 + b0f);
    o.y = f2bf((tile[jc + 1][i] - m) * rr * g1 + b1f);
    o.z = f2bf((tile[jc + 2][i] - m) * rr * g2 + b2f);
    o.w = f2bf((tile[jc + 3][i] - m) * rr * g3 + b3f);
    __builtin_nontemporal_store(o, (u16x4*)(y2c + ((size_t)bl * N_ + n) * C_ + c0 + jc));
  }
}

// ---------------- K2: dual-A gated GEMM, split q / kv ----------------
// MODE 0: q columns (grid.y=6, writes o_nd=[bl,h,n,d]).
// MODE 1: kv columns (grid.y=12, k -> o_kd, v -> o_vT transposed).
template <int MODE>
__global__ __launch_bounds__(256, 2) void gemm_gate(
    const u16* __restrict__ xbc, const u16* __restrict__ y2c,
    const u16* __restrict__ wb, const float* __restrict__ bias_,
    u16* __restrict__ o_nd, u16* __restrict__ o_kd, u16* __restrict__ o_vT) {
  __shared__ u16 smem[128 * 136];      // K-loop uses first 12288 u16
  u16* Ax = smem;
  u16* Ay = smem + 4096;
  u16* Bs = smem + 8192;
  int t = threadIdx.x, l = t & 63;
  int quad = l >> 4, l15 = l & 15;
  int w = t >> 6, wm = w & 1, wn = w >> 1;
  int m0l = blockIdx.x * 128;
  int n0l = blockIdx.y * 128;
  const u16* wp = wb + (size_t)n0l * C_;
  const float* bp = bias_ + n0l;
  const int sel = (MODE == 0) ? 0 : (n0l < C_ ? 1 : 2);
  const int h0 = (sel == 2 ? (n0l - C_) : n0l) >> 6;

  f4 accx[4][4], accy[4][4];
  for (int i = 0; i < 4; ++i)
    for (int j = 0; j < 4; ++j) {
      accx[i][j] = (f4){0.f, 0.f, 0.f, 0.f};
      accy[i][j] = (f4){0.f, 0.f, 0.f, 0.f};
    }

  int row = t >> 2, colb = (t & 3) * 8;
  const u16* gx = xbc + (size_t)(m0l + row) * C_ + colb;
  const u16* gy = y2c + (size_t)(m0l + row) * C_ + colb;
  const u16* gw = wp + (size_t)row * C_ + colb;

  for (int kk = 0; kk < C_; kk += 32) {
    __syncthreads();
    g2l16(gx + kk,           Ax + t * 8);
    g2l16(gx + kk + 64 * C_, Ax + 2048 + t * 8);
    g2l16(gy + kk,           Ay + t * 8);
    g2l16(gy + kk + 64 * C_, Ay + 2048 + t * 8);
    g2l16(gw + kk,           Bs + t * 8);
    g2l16(gw + kk + 64 * C_, Bs + 2048 + t * 8);
    __syncthreads();
    bf16x8 afx[4], afy[4], bfr[4];
    for (int i = 0; i < 4; ++i) {
      int ra = (wm * 64 + i * 16 + l15) * 32 + quad * 8;
      afx[i] = *(const bf16x8*)&Ax[ra];
      afy[i] = *(const bf16x8*)&Ay[ra];
      int rb = (wn * 64 + i * 16 + l15) * 32 + quad * 8;
      bfr[i] = *(const bf16x8*)&Bs[rb];
    }
    for (int i = 0; i < 4; ++i)
      for (int j = 0; j < 4; ++j) {
        accx[i][j] = __builtin_amdgcn_mfma_f32_16x16x32_bf16(afx[i], bfr[j], accx[i][j], 0, 0, 0);
        accy[i][j] = __builtin_amdgcn_mfma_f32_16x16x32_bf16(afy[i], bfr[j], accy[i][j], 0, 0, 0);
      }
  }

  // epilogue: gate -> LDS tile -> 16-B nontemporal stores
  __syncthreads();
  const int PITCH = 136;
  for (int j = 0; j < 4; ++j) {
    int cloc = wn * 64 + j * 16 + l15;
    float bias = bp[cloc];
    for (int i = 0; i < 4; ++i) {
      int rb0 = wm * 64 + i * 16 + quad * 4;
      for (int r = 0; r < 4; ++r) {
        int rloc = rb0 + r;
        float vx = accx[i][j][r] + bias;
        float vy = accy[i][j][r] + bias;
        float gg = 1.f / (1.f + __expf(-vy));
        float val = (sel == 0) ? vx * (1.f + gg) : gg * (vx + 1.f);
        u16 bv = f2bf(val);
        if (sel == 2) smem[cloc * PITCH + rloc] = bv;   // v staged transposed
        else          smem[rloc * PITCH + cloc] = bv;
      }
    }
  }
  __syncthreads();
  {
    int rr = t >> 1, hh = t & 1;
    const u16* src = smem + rr * PITCH + hh * 64;
    u16* dst;
    if (sel == 2) {
      int h = h0 + (rr >> 6), d = rr & 63;
      int bl = m0l >> 10, nbase = m0l & 1023;
      dst = o_vT + (size_t)((bl * NH + h) * HD + d) * N_ + nbase + hh * 64;
    } else {
      int gml = m0l + rr;
      int bl = gml >> 10, n = gml & 1023;
      int h = h0 + hh;
      dst = (sel == 0 ? o_nd : o_kd) + (size_t)((bl * NH + h) * N_ + n) * HD;
    }
    for (int c = 0; c < 8; ++c) {
      bf16x8 v = *(const bf16x8*)(src + c * 8);
      __builtin_nontemporal_store(v, (bf16x8*)(dst + c * 8));
    }
  }
}

// ---------------- K3: fused attention ----------------
__global__ __launch_bounds__(256) void attn(const u16* __restrict__ qoc,
                                            const u16* __restrict__ koc,
                                            const u16* __restrict__ vTc,
                                            u16* __restrict__ aoc) {
  __shared__ u16 Qs[64 * 64], Ks[64 * 64], Vs[64 * 64];
  __shared__ u16 Ps[64 * 72];
  int t = threadIdx.x, l = t & 63, w = t >> 6;
  int quad = l >> 4, l15 = l & 15;
  int bhl = blockIdx.y;
  int bl = bhl / NH, h = bhl % NH;
  int q0 = blockIdx.x * 64;
  const u16* qbp = qoc + ((size_t)bhl * N_ + q0) * HD;
  g2l16(qbp + (t >> 3) * HD + (t & 7) * 8,        Qs + t * 8);
  g2l16(qbp + (32 + (t >> 3)) * HD + (t & 7) * 8, Qs + 2048 + t * 8);
  __syncthreads();
  bf16x8 aq0 = *(const bf16x8*)&Qs[(w * 16 + l15) * 64 + quad * 8];
  bf16x8 aq1 = *(const bf16x8*)&Qs[(w * 16 + l15) * 64 + 32 + quad * 8];
  f4 o[4];
  for (int i = 0; i < 4; ++i) o[i] = (f4){0.f, 0.f, 0.f, 0.f};
  float lsum[4] = {0.f, 0.f, 0.f, 0.f};
  const u16* kb = koc + (size_t)bhl * N_ * HD;
  const u16* vb = vTc + (size_t)bhl * HD * N_;
  for (int kt = 0; kt < 16; ++kt) {
    int key0 = kt * 64;
    __syncthreads();
    g2l16(kb + (size_t)(key0 + (t >> 3)) * HD + (t & 7) * 8,      Ks + t * 8);
    g2l16(kb + (size_t)(key0 + 32 + (t >> 3)) * HD + (t & 7) * 8, Ks + 2048 + t * 8);
    g2l16(vb + (size_t)(t >> 3) * N_ + key0 + (t & 7) * 8,        Vs + t * 8);
    g2l16(vb + (size_t)(32 + (t >> 3)) * N_ + key0 + (t & 7) * 8, Vs + 2048 + t * 8);
    __syncthreads();
    f4 s[4];
    for (int ni = 0; ni < 4; ++ni) {
      bf16x8 b0v = *(const bf16x8*)&Ks[(ni * 16 + l15) * 64 + quad * 8];
      bf16x8 b1v = *(const bf16x8*)&Ks[(ni * 16 + l15) * 64 + 32 + quad * 8];
      f4 z = (f4){0.f, 0.f, 0.f, 0.f};
      z = __builtin_amdgcn_mfma_f32_16x16x32_bf16(aq0, b0v, z, 0, 0, 0);
      z = __builtin_amdgcn_mfma_f32_16x16x32_bf16(aq1, b1v, z, 0, 0, 0);
      s[ni] = z;
    }
    float p[4][4];
    for (int ni = 0; ni < 4; ++ni)
      for (int r = 0; r < 4; ++r)
        p[ni][r] = __expf(s[ni][r] * 0.125f);
    for (int r = 0; r < 4; ++r) {
      float ts = p[0][r] + p[1][r] + p[2][r] + p[3][r];
      ts += __shfl_xor(ts, 1);
      ts += __shfl_xor(ts, 2);
      ts += __shfl_xor(ts, 4);
      ts += __shfl_xor(ts, 8);
      lsum[r] += ts;
    }
    for (int ni = 0; ni < 4; ++ni)
      for (int r = 0; r < 4; ++r)
        Ps[(w * 16 + quad * 4 + r) * 72 + ni * 16 + l15] = f2bf(p[ni][r]);
    bf16x8 ap0 = *(const bf16x8*)&Ps[(w * 16 + l15) * 72 + quad * 8];
    bf16x8 ap1 = *(const bf16x8*)&Ps[(w * 16 + l15) * 72 + 32 + quad * 8];
    for (int ni = 0; ni < 4; ++ni) {
      bf16x8 b0v = *(const bf16x8*)&Vs[(ni * 16 + l15) * 64 + quad * 8];
      bf16x8 b1v = *(const bf16x8*)&Vs[(ni * 16 + l15) * 64 + 32 + quad * 8];
      o[ni] = __builtin_amdgcn_mfma_f32_16x16x32_bf16(ap0, b0v, o[ni], 0, 0, 0);
      o[ni] = __builtin_amdgcn_mfma_f32_16x16x32_bf16(ap1, b1v, o[ni], 0, 0, 0);
    }
  }
  for (int ni = 0; ni < 4; ++ni)
    for (int r = 0; r < 4; ++r)
      Ps[(w * 16 + quad * 4 + r) * 72 + ni * 16 + l15] =
          f2bf(o[ni][r] / lsum[r]);
  __syncthreads();
  {
    int rr = t >> 2, cc = t & 3;
    int n = q0 + rr;
    const u16* src = Ps + rr * 72 + cc * 16;
    u16* dst = aoc + ((size_t)bl * N_ + n) * C_ + h * HD + cc * 16;
    __builtin_nontemporal_store(*(const bf16x8*)src, (bf16x8*)dst);
    __builtin_nontemporal_store(*(const bf16x8*)(src + 8), (bf16x8*)(dst + 8));
  }
}

// ---------------- K4: output projection GEMM ----------------
__global__ __launch_bounds__(256, 2) void gemm_proj(const u16* __restrict__ aoc,
                                                    const u16* __restrict__ pwb,
                                                    const float* __restrict__ bias,
                                                    float* __restrict__ out,
                                                    int b0) {
  __shared__ u16 As[128 * 32], Bs[128 * 32];
  int t = threadIdx.x, l = t & 63;
  int quad = l >> 4, l15 = l & 15;
  int w = t >> 6, wm = w & 1, wn = w >> 1;
  int m0l = blockIdx.x * 128, n0 = blockIdx.y * 128;
  f4 acc[4][4];
  for (int i = 0; i < 4; ++i)
    for (int j = 0; j < 4; ++j) acc[i][j] = (f4){0.f, 0.f, 0.f, 0.f};
  int row = t >> 2, colb = (t & 3) * 8;
  const u16* ga = aoc + (size_t)(m0l + row) * C_ + colb;
  const u16* gw = pwb + (size_t)(n0 + row) * C_ + colb;
  for (int kk = 0; kk < C_; kk += 32) {
    __syncthreads();
    g2l16(ga + kk,           As + t * 8);
    g2l16(ga + kk + 64 * C_, As + 2048 + t * 8);
    g2l16(gw + kk,           Bs + t * 8);
    g2l16(gw + kk + 64 * C_, Bs + 2048 + t * 8);
    __syncthreads();
    bf16x8 af[4], bfr[4];
    for (int i = 0; i < 4; ++i) {
      af[i]  = *(const bf16x8*)&As[(wm * 64 + i * 16 + l15) * 32 + quad * 8];
      bfr[i] = *(const bf16x8*)&Bs[(wn * 64 + i * 16 + l15) * 32 + quad * 8];
    }
    for (int i = 0; i < 4; ++i)
      for (int j = 0; j < 4; ++j)
        acc[i][j] = __builtin_amdgcn_mfma_f32_16x16x32_bf16(af[i], bfr[j], acc[i][j], 0, 0, 0);
  }
  for (int j = 0; j < 4; ++j) {
    int gcol = n0 + wn * 64 + j * 16 + l15;
    float bv = bias[gcol];
    for (int i = 0; i < 4; ++i) {
      int rbase = m0l + wm * 64 + i * 16 + quad * 4;
      for (int r = 0; r < 4; ++r)
        __builtin_nontemporal_store(acc[i][j][r] + bv,
                                    &out[(size_t)(b0 * N_ + rbase + r) * C_ + gcol]);
    }
  }
}

extern "C" void kernel_launch(void* const* d_in, const int* in_sizes, int n_in,
                              void* d_out, int out_size, void* d_ws, size_t ws_size,
                              hipStream_t stream) {
  const float* x   = (const float*)d_in[0];
  const float* y   = (const float*)d_in[1];
  const float* qw  = (const float*)d_in[2];
  const float* qb  = (const float*)d_in[3];
  const float* kvw = (const float*)d_in[4];
  const float* kvb = (const float*)d_in[5];
  const float* pw  = (const float*)d_in[6];
  const float* pb  = (const float*)d_in[7];
  const float* lg  = (const float*)d_in[8];
  const float* lb  = (const float*)d_in[9];

  char* ws = (char*)d_ws;
  float* mu = (float*)(ws);
  float* rs = (float*)(ws + 32768);
  u16* qwb  = (u16*)(ws + 65536);
  u16* kvwb = (u16*)(ws + 1245184);
  u16* pwb  = (u16*)(ws + 3604480);
  const size_t BASE2 = 4784128;
  const size_t PER_B = 1572864;

  int nb = 1;
  for (int c = 8; c >= 1; c >>= 1) {
    if (BASE2 + 5 * (size_t)c * PER_B <= ws_size) { nb = c; break; }
  }
  u16* xbc = (u16*)(ws + BASE2);
  u16* y2c = (u16*)(ws + BASE2 + (size_t)nb * PER_B);
  u16* qoc = (u16*)(ws + BASE2 + 2 * (size_t)nb * PER_B);
  u16* koc = (u16*)(ws + BASE2 + 3 * (size_t)nb * PER_B);
  u16* vTc = (u16*)(ws + BASE2 + 4 * (size_t)nb * PER_B);
  u16* aoc = xbc;

  cvt_bf16<<<dim3(576), dim3(256), 0, stream>>>(qw, qwb, 147456);
  cvt_bf16<<<dim3(1152), dim3(256), 0, stream>>>(kvw, kvwb, 294912);
  cvt_bf16<<<dim3(576), dim3(256), 0, stream>>>(pw, pwb, 147456);

  for (int b0 = 0; b0 < B_; b0 += nb) {
    cvt_bf16<<<dim3(768 * nb), dim3(256), 0, stream>>>(
        x + (size_t)b0 * N_ * C_, xbc, nb * 196608);
    ln_stats<<<dim3(16 * nb), dim3(256), 0, stream>>>(y, mu, rs, b0);
    ln_apply<<<dim3(16, 12, nb), dim3(256), 0, stream>>>(y, mu, rs, lg, lb, y2c, b0);
    gemm_gate<0><<<dim3(8 * nb, 6), dim3(256), 0, stream>>>(xbc, y2c, qwb, qb,
                                                            qoc, nullptr, nullptr);
    gemm_gate<1><<<dim3(8 * nb, 12), dim3(256), 0, stream>>>(xbc, y2c, kvwb, kvb,
                                                             nullptr, koc, vTc);
    attn<<<dim3(16, 12 * nb), dim3(256), 0, stream>>>(qoc, koc, vTc, aoc);
    gemm_proj<<<dim3(8 * nb, 6), dim3(256), 0, stream>>>(aoc, pwb, pb, (float*)d_out, b0);
  }
}